// Round 13
// baseline (94.094 us; speedup 1.0000x reference)
//
#include <hip/hip_runtime.h>

#define BB 8
#define TT 256
#define DD 512
#define AA 512

#define PS 2.8853900817779268f   // 2*log2(e)
#define LOG2E 1.4426950408889634f

typedef __attribute__((ext_vector_type(8))) short short8;
typedef __attribute__((ext_vector_type(4))) float f32x4;

__device__ __forceinline__ float fast_tanh(float x) {
    float e = __builtin_amdgcn_exp2f(x * PS);
    float r = __builtin_amdgcn_rcpf(1.0f + e);
    return fmaf(-2.0f, r, 1.0f);
}

__device__ __forceinline__ ushort f2bf(float x) {
    uint u = __float_as_uint(x);
    uint r = (u + 0x7fffu + ((u >> 16) & 1u)) >> 16;  // RNE
    return (ushort)r;
}
__device__ __forceinline__ float bf2f(ushort h) {
    return __uint_as_float(((uint)h) << 16);
}

#define ABYTE(k0) (((k0) < 1024 ? (k0) : (k0) - 1024) * 2)
#define BBYTE(k0) (((k0) < 512 ? (k0) : (k0) - 512) * 2)

// ---------------- prep: k0 (blocks 0..15) + conv_W (16..783) + conv_A (784..1807) --------
__global__ __launch_bounds__(256) void prep(const float* __restrict__ SO,
                                            ushort* __restrict__ Ast,
                                            const float* __restrict__ Wsh,
                                            const float* __restrict__ Wsi,
                                            const float* __restrict__ Wih,
                                            ushort* __restrict__ Wt,
                                            const float* __restrict__ fs_g,
                                            const float* __restrict__ Wii,
                                            const float* __restrict__ bii,
                                            float* __restrict__ ii) {
    const int bid = blockIdx.x;
    const int tid = threadIdx.x;
    __shared__ float T[32][33];
    __shared__ float fs[DD];

    if (bid < 16) {
        int b = bid >> 1, half = bid & 1;
        int a = half * 256 + tid;
        fs[tid]       = fs_g[b * DD + tid];
        fs[tid + 256] = fs_g[b * DD + tid + 256];
        __syncthreads();
        float acc = bii[a];
        #pragma unroll 8
        for (int d = 0; d < DD; ++d)
            acc = fmaf(fs[d], Wii[(size_t)d * AA + a], acc);
        ii[b * AA + a] = acc;
    } else if (bid < 784) {
        int lbid = bid - 16;
        int z = lbid >> 8;
        int rem = lbid & 255;
        const float* W = (z == 0) ? Wsh : (z == 1) ? Wsi : Wih;
        int k0 = (rem & 15) * 32, n0 = (rem >> 4) * 32;
        int tx = tid & 31, ty = tid >> 5;
        #pragma unroll
        for (int r = 0; r < 4; ++r) {
            int kl = ty * 4 + r;
            T[kl][tx] = W[(size_t)(k0 + kl) * 512 + n0 + tx];
        }
        __syncthreads();
        size_t nbase = (size_t)z * 512 + n0;
        #pragma unroll
        for (int r = 0; r < 4; ++r) {
            int nl = ty * 4 + r;
            float v = T[tx][nl];
            ushort hi = f2bf(v);
            ushort lo = f2bf(v - bf2f(hi));
            Wt[(nbase + nl) * 1024 + k0 + tx]       = hi;
            Wt[(nbase + nl) * 1024 + 512 + k0 + tx] = lo;
        }
    } else {
        int qid = (bid - 784) * 256 + tid;
        int m = qid >> 7;
        int k4 = (qid & 127) * 4;
        float4 v = *reinterpret_cast<const float4*>(&SO[(size_t)m * 512 + k4]);
        ushort4 hi, lo;
        hi.x = f2bf(v.x); lo.x = f2bf(v.x - bf2f(hi.x));
        hi.y = f2bf(v.y); lo.y = f2bf(v.y - bf2f(hi.y));
        hi.z = f2bf(v.z); lo.z = f2bf(v.z - bf2f(hi.z));
        hi.w = f2bf(v.w); lo.w = f2bf(v.w - bf2f(hi.w));
        *reinterpret_cast<ushort4*>(&Ast[(size_t)m * 1024 + k4])       = hi;
        *reinterpret_cast<ushort4*>(&Ast[(size_t)m * 1024 + 512 + k4]) = lo;
    }
}

// ---------------- gemm_mfma: 64x64 tile, BK=64, LDS dbuf + depth-2 reg prefetch ----------
__global__ __launch_bounds__(256) void gemm_mfma(
    const ushort* __restrict__ Ast, const ushort* __restrict__ Wt,
    const float* __restrict__ bsh, const float* __restrict__ bsi,
    const float* __restrict__ bih,
    const float* __restrict__ ii, const float* __restrict__ iv,
    float* __restrict__ EhT, float* __restrict__ Es, float* __restrict__ ipart) {
    __shared__ __align__(16) ushort Al[2][64 * 64];
    __shared__ __align__(16) ushort Bl[2][64 * 64];
    const int tid = threadIdx.x;
    const int wave = tid >> 6, lane = tid & 63;
    const int wr = wave >> 1, wc = wave & 1;
    const int m0 = blockIdx.x * 64;
    const int by = blockIdx.y;
    const int n0 = by * 64;
    const int l15 = lane & 15, kb = lane >> 4;

    f32x4 acc[2][2] = {};

    const char* Ab = reinterpret_cast<const char*>(Ast);
    const char* Bb = reinterpret_cast<const char*>(Wt);
    char* AlB = reinterpret_cast<char*>(&Al[0][0]);
    char* BlB = reinterpret_cast<char*>(&Bl[0][0]);

    const int srow = tid >> 2, sslot = tid & 3;
    const int lw0 = srow * 128 + (((sslot    ) ^ (srow & 7)) * 16);
    const int lw1 = srow * 128 + (((sslot + 4) ^ (srow & 7)) * 16);
    const char* agp = Ab + (size_t)(m0 + srow) * 2048 + sslot * 16;
    const char* bgp = Bb + (size_t)(n0 + srow) * 2048 + sslot * 16;

    int aro[2][2], bro[2][2];
    #pragma unroll
    for (int i = 0; i < 2; ++i) {
        int ra = wr * 32 + i * 16 + l15;
        int rb = wc * 32 + i * 16 + l15;
        #pragma unroll
        for (int kk = 0; kk < 2; ++kk) {
            aro[kk][i] = ra * 128 + (((kk * 4 + kb) ^ (ra & 7)) * 16);
            bro[kk][i] = rb * 128 + (((kk * 4 + kb) ^ (rb & 7)) * 16);
        }
    }

    #define GLOAD4(H, S) do {                                        \
        const int k0_ = (S) * 64;                                    \
        const int ab_ = ABYTE(k0_), bb_ = BBYTE(k0_);                \
        H[0] = *reinterpret_cast<const short8*>(agp + ab_);          \
        H[1] = *reinterpret_cast<const short8*>(agp + ab_ + 64);     \
        H[2] = *reinterpret_cast<const short8*>(bgp + bb_);          \
        H[3] = *reinterpret_cast<const short8*>(bgp + bb_ + 64);     \
    } while (0)

    #define STLDS(BUF, H) do {                                       \
        char* An_ = AlB + (BUF) * 8192;                              \
        char* Bn_ = BlB + (BUF) * 8192;                              \
        *reinterpret_cast<short8*>(An_ + lw0) = H[0];                \
        *reinterpret_cast<short8*>(An_ + lw1) = H[1];                \
        *reinterpret_cast<short8*>(Bn_ + lw0) = H[2];                \
        *reinterpret_cast<short8*>(Bn_ + lw1) = H[3];                \
    } while (0)

    short8 hld[2][4];
    GLOAD4(hld[0], 0);
    STLDS(0, hld[0]);
    GLOAD4(hld[1], 1);
    __syncthreads();

    #pragma unroll
    for (int it = 0; it < 24; ++it) {
        if (it + 2 < 24) GLOAD4(hld[it & 1], it + 2);
        const char* Ac = AlB + (it & 1) * 8192;
        const char* Bc = BlB + (it & 1) * 8192;
        #pragma unroll
        for (int kk = 0; kk < 2; ++kk) {
            short8 af[2], bf[2];
            #pragma unroll
            for (int i = 0; i < 2; ++i) {
                af[i] = *reinterpret_cast<const short8*>(Ac + aro[kk][i]);
                bf[i] = *reinterpret_cast<const short8*>(Bc + bro[kk][i]);
            }
            #pragma unroll
            for (int i = 0; i < 2; ++i)
                #pragma unroll
                for (int j = 0; j < 2; ++j)
                    acc[i][j] = __builtin_amdgcn_mfma_f32_16x16x32_bf16(
                        af[i], bf[j], acc[i][j], 0, 0, 0);
        }
        if (it + 1 < 24) STLDS((it + 1) & 1, hld[(it + 1) & 1]);
        __syncthreads();
    }

    const int b = m0 >> 8;
    if (by < 8) {
        #pragma unroll
        for (int i = 0; i < 2; ++i) {
            int t0 = (m0 & 255) + wr * 32 + i * 16 + kb * 4;
            #pragma unroll
            for (int j = 0; j < 2; ++j) {
                int n = n0 + wc * 32 + j * 16 + l15;
                float bbv = bsh[n];
                float4 v;
                v.x = __builtin_amdgcn_exp2f((acc[i][j][0] + bbv) * PS);
                v.y = __builtin_amdgcn_exp2f((acc[i][j][1] + bbv) * PS);
                v.z = __builtin_amdgcn_exp2f((acc[i][j][2] + bbv) * PS);
                v.w = __builtin_amdgcn_exp2f((acc[i][j][3] + bbv) * PS);
                *reinterpret_cast<float4*>(&EhT[((size_t)b * 512 + n) * 256 + t0]) = v;
            }
        }
    } else if (by < 16) {
        #pragma unroll
        for (int i = 0; i < 2; ++i) {
            #pragma unroll
            for (int j = 0; j < 2; ++j) {
                int n = n0 - 512 + wc * 32 + j * 16 + l15;
                float bbv = bsi[n];
                #pragma unroll
                for (int r = 0; r < 4; ++r) {
                    int m = m0 + wr * 32 + i * 16 + kb * 4 + r;
                    Es[(size_t)m * 512 + n] = __builtin_amdgcn_exp2f((acc[i][j][r] + bbv) * PS);
                }
            }
        }
    } else {
        int slot = (by - 16) * 2 + wc;
        #pragma unroll
        for (int i = 0; i < 2; ++i) {
            float p0 = 0.f, p1 = 0.f, p2 = 0.f, p3 = 0.f;
            #pragma unroll
            for (int j = 0; j < 2; ++j) {
                int n = n0 - 1024 + wc * 32 + j * 16 + l15;
                float add = bih[n] + ii[b * 512 + n];
                float w = iv[n];
                p0 = fmaf(w, fast_tanh(acc[i][j][0] + add), p0);
                p1 = fmaf(w, fast_tanh(acc[i][j][1] + add), p1);
                p2 = fmaf(w, fast_tanh(acc[i][j][2] + add), p2);
                p3 = fmaf(w, fast_tanh(acc[i][j][3] + add), p3);
            }
            #pragma unroll
            for (int off = 1; off < 16; off <<= 1) {
                p0 += __shfl_xor(p0, off);
                p1 += __shfl_xor(p1, off);
                p2 += __shfl_xor(p2, off);
                p3 += __shfl_xor(p3, off);
            }
            int mb = m0 + wr * 32 + i * 16 + kb * 4;
            if (l15 == 0) ipart[slot * 2048 + mb + 0] = p0;
            if (l15 == 1) ipart[slot * 2048 + mb + 1] = p1;
            if (l15 == 2) ipart[slot * 2048 + mb + 2] = p2;
            if (l15 == 3) ipart[slot * 2048 + mb + 3] = p3;
        }
    }
}

// ---------------- fallback fp32 GEMM path ----------------
#define TS 64
#define KS 16
#define LPAD 72

__global__ __launch_bounds__(256) void k0_ii(const float* __restrict__ fs_g,
                                             const float* __restrict__ Wii,
                                             const float* __restrict__ bii,
                                             float* __restrict__ ii) {
    int b = blockIdx.x, tid = threadIdx.x;
    int a = blockIdx.y * 256 + tid;
    __shared__ float fs[DD];
    fs[tid]       = fs_g[b * DD + tid];
    fs[tid + 256] = fs_g[b * DD + tid + 256];
    __syncthreads();
    float acc = bii[a];
    #pragma unroll 8
    for (int d = 0; d < DD; ++d)
        acc = fmaf(fs[d], Wii[(size_t)d * AA + a], acc);
    ii[b * AA + a] = acc;
}

__global__ __launch_bounds__(256) void k1_gemm_old(
    const float* __restrict__ SO,
    const float* __restrict__ Wsh, const float* __restrict__ bsh,
    const float* __restrict__ Wsi, const float* __restrict__ bsi,
    const float* __restrict__ Wih, const float* __restrict__ bih,
    const float* __restrict__ ii, const float* __restrict__ iv,
    float* __restrict__ EhT, float* __restrict__ Es, float* __restrict__ ipart) {
    const int mode = blockIdx.z;
    const float* W;
    const float* bias;
    if (mode == 0)      { W = Wsh; bias = bsh; }
    else if (mode == 1) { W = Wsi; bias = bsi; }
    else                { W = Wih; bias = bih; }

    const int m0 = blockIdx.x * TS;
    const int n0 = blockIdx.y * TS;
    const int tid = threadIdx.x;
    const int tx = tid & 15, ty = tid >> 4;

    __shared__ __align__(16) float As[KS][LPAD];
    __shared__ __align__(16) float Bs[KS][LPAD];
    __shared__ __align__(16) float Cs[TS][LPAD];

    float acc[4][4] = {};
    const int arow = tid >> 2;
    const int akc  = (tid & 3) * 4;
    const int brw  = tid >> 4;
    const int bnc  = (tid & 15) * 4;

    for (int k0 = 0; k0 < DD; k0 += KS) {
        float4 av = *reinterpret_cast<const float4*>(&SO[(m0 + arow) * DD + k0 + akc]);
        As[akc + 0][arow] = av.x;
        As[akc + 1][arow] = av.y;
        As[akc + 2][arow] = av.z;
        As[akc + 3][arow] = av.w;
        float4 bv = *reinterpret_cast<const float4*>(&W[(k0 + brw) * AA + n0 + bnc]);
        *reinterpret_cast<float4*>(&Bs[brw][bnc]) = bv;
        __syncthreads();
        #pragma unroll
        for (int kk = 0; kk < KS; ++kk) {
            float4 a4 = *reinterpret_cast<const float4*>(&As[kk][ty * 4]);
            float4 b4 = *reinterpret_cast<const float4*>(&Bs[kk][tx * 4]);
            float av_[4] = {a4.x, a4.y, a4.z, a4.w};
            float bv_[4] = {b4.x, b4.y, b4.z, b4.w};
            #pragma unroll
            for (int i = 0; i < 4; ++i)
                #pragma unroll
                for (int j = 0; j < 4; ++j)
                    acc[i][j] = fmaf(av_[i], bv_[j], acc[i][j]);
        }
        __syncthreads();
    }

    if (mode == 1) {
        #pragma unroll
        for (int i = 0; i < 4; ++i) {
            int m = m0 + ty * 4 + i;
            float4 v;
            v.x = __builtin_amdgcn_exp2f((acc[i][0] + bias[n0 + tx * 4 + 0]) * PS);
            v.y = __builtin_amdgcn_exp2f((acc[i][1] + bias[n0 + tx * 4 + 1]) * PS);
            v.z = __builtin_amdgcn_exp2f((acc[i][2] + bias[n0 + tx * 4 + 2]) * PS);
            v.w = __builtin_amdgcn_exp2f((acc[i][3] + bias[n0 + tx * 4 + 3]) * PS);
            *reinterpret_cast<float4*>(&Es[(size_t)m * AA + n0 + tx * 4]) = v;
        }
    } else if (mode == 0) {
        #pragma unroll
        for (int i = 0; i < 4; ++i)
            #pragma unroll
            for (int j = 0; j < 4; ++j)
                Cs[tx * 4 + j][ty * 4 + i] =
                    __builtin_amdgcn_exp2f((acc[i][j] + bias[n0 + tx * 4 + j]) * PS);
        __syncthreads();
        int row = tid >> 2, part = tid & 3;
        int bb = m0 >> 8;
        int tstart = (m0 & 255) + part * 16;
        float* dst = &EhT[bb * (AA * TT) + (n0 + row) * TT + tstart];
        #pragma unroll
        for (int q = 0; q < 4; ++q) {
            float4 v = *reinterpret_cast<const float4*>(&Cs[row][part * 16 + q * 4]);
            *reinterpret_cast<float4*>(&dst[q * 4]) = v;
        }
    } else {
        int bb = m0 >> 8;
        #pragma unroll
        for (int i = 0; i < 4; ++i) {
            float p = 0.f;
            #pragma unroll
            for (int j = 0; j < 4; ++j) {
                int n = n0 + tx * 4 + j;
                float x = acc[i][j] + bias[n] + ii[bb * AA + n];
                p = fmaf(iv[n], fast_tanh(x), p);
            }
            Cs[ty * 4 + i][tx] = p;
        }
        __syncthreads();
        if (tid < 64) {
            float s = 0.f;
            #pragma unroll
            for (int k = 0; k < 16; ++k) s += Cs[tid][k];
            ipart[blockIdx.y * 2048 + m0 + tid] = s;
        }
    }
}

// ---------------- k3_fused: pairwise-rcp + FULL operand register pipeline ----------------
// 512 slot blocks (2/CU); thread = (s-pair sp=tid&127, a-quarter ah=tid>>7).
// est/sv LDS reads and h global reads are all prefetched one 4-a stage ahead.
__global__ __launch_bounds__(512, 4) void k3_fused(const float* __restrict__ SO,
                                                   const float* __restrict__ EhT,
                                                   const float* __restrict__ Es,
                                                   const float* __restrict__ sv_g,
                                                   const float* __restrict__ ipart,
                                                   float* __restrict__ out_cslot,
                                                   float* __restrict__ out_cint,
                                                   int npart) {
    const int bid = blockIdx.x;
    const int tid = threadIdx.x;

    __shared__ __align__(16) float est[512][4];   // [a][q]
    __shared__ __align__(16) float sv[512];
    __shared__ __align__(8)  float yp[4][4][256]; // [ah][q][s]
    __shared__ __align__(16) float wlt[256][4];
    __shared__ float redm[4][2];
    __shared__ float reds[4][2];
    __shared__ float redI[256];
    __shared__ float wlI[256];

    const int b = bid & 7;          // XCD-affine
    const int t0 = (bid >> 3) * 4;
    const int sp = tid & 127;       // s-pair index: s = 2*sp, 2*sp+1
    const int ah = tid >> 7;        // 0..3, a-quarter
    const int abase = ah * 128;

    // stage est (transposed gather) + sv
    {
        const float* esrc = &Es[(size_t)(b * 256 + t0) * 512];
        #pragma unroll
        for (int i = tid; i < 2048; i += 512) est[i & 511][i >> 9] = esrc[i];
        sv[tid] = sv_g[tid];
    }
    __syncthreads();

    // ---- score: 128 a x 4 t x 2 s per thread; a-pairs share one rcp ----
    const float* hp = &EhT[((size_t)b * 512 + abase) * 256 + 2 * sp];
    float a00=0.f,a01=0.f,a10=0.f,a11=0.f,a20=0.f,a21=0.f,a30=0.f,a31=0.f;

    // one (t) slice of a pair: two s-values, shared va/vb
    #define PAIRT(HA, HB, E1, E2, VA, VB, ACC0, ACC1) do {                         \
        float d1x = fmaf((HA).x, (E1), 1.f);                                       \
        float d2x = fmaf((HB).x, (E2), 1.f);                                       \
        ACC0 = fmaf(fmaf((VA), d2x, (VB) * d1x),                                   \
                    __builtin_amdgcn_rcpf(d1x * d2x), ACC0);                       \
        float d1y = fmaf((HA).y, (E1), 1.f);                                       \
        float d2y = fmaf((HB).y, (E2), 1.f);                                       \
        ACC1 = fmaf(fmaf((VA), d2y, (VB) * d1y),                                   \
                    __builtin_amdgcn_rcpf(d1y * d2y), ACC1);                       \
    } while (0)

    // compute one 4-a stage from registers H(float2[4]), E(float4[4]), V(float4)
    #define SCOREC(H, E, V) do {                                                   \
        PAIRT(H[0], H[1], E[0].x, E[1].x, (V).x, (V).y, a00, a01);                 \
        PAIRT(H[0], H[1], E[0].y, E[1].y, (V).x, (V).y, a10, a11);                 \
        PAIRT(H[0], H[1], E[0].z, E[1].z, (V).x, (V).y, a20, a21);                 \
        PAIRT(H[0], H[1], E[0].w, E[1].w, (V).x, (V).y, a30, a31);                 \
        PAIRT(H[2], H[3], E[2].x, E[3].x, (V).z, (V).w, a00, a01);                 \
        PAIRT(H[2], H[3], E[2].y, E[3].y, (V).z, (V).w, a10, a11);                 \
        PAIRT(H[2], H[3], E[2].z, E[3].z, (V).z, (V).w, a20, a21);                 \
        PAIRT(H[2], H[3], E[2].w, E[3].w, (V).z, (V).w, a30, a31);                 \
    } while (0)

    #define LOADSTAGE(H, E, V, A0G, A0L) do {                                      \
        _Pragma("unroll")                                                          \
        for (int u_ = 0; u_ < 4; ++u_) {                                           \
            H[u_] = *reinterpret_cast<const float2*>(&hp[((A0G) + u_) * 256]);     \
            E[u_] = *reinterpret_cast<const float4*>(&est[abase + (A0L) + u_][0]); \
        }                                                                          \
        V = *reinterpret_cast<const float4*>(&sv[abase + (A0L)]);                  \
    } while (0)

    float2 ha[4], hb[4], hA[4], hB[4];
    float4 ea[4], eb[4], eA[4], eB[4];
    float4 va, vb_, vA, vB;

    LOADSTAGE(ha, ea, va, 0, 0);
    LOADSTAGE(hb, eb, vb_, 4, 4);

    for (int a0 = 0; a0 < 128; a0 += 8) {
        // prefetch stage a0+8 (h over-read stays inside ws; est/sv wrapped)
        LOADSTAGE(hA, eA, vA, a0 + 8, (a0 + 8) & 127);
        SCOREC(ha, ea, va);
        // prefetch stage a0+12
        LOADSTAGE(hB, eB, vB, a0 + 12, (a0 + 12) & 127);
        SCOREC(hb, eb, vb_);
        #pragma unroll
        for (int u = 0; u < 4; ++u) {
            ha[u] = hA[u]; ea[u] = eA[u];
            hb[u] = hB[u]; eb[u] = eB[u];
        }
        va = vA; vb_ = vB;
    }

    *reinterpret_cast<float2*>(&yp[ah][0][2 * sp]) = make_float2(a00, a01);
    *reinterpret_cast<float2*>(&yp[ah][1][2 * sp]) = make_float2(a10, a11);
    *reinterpret_cast<float2*>(&yp[ah][2][2 * sp]) = make_float2(a20, a21);
    *reinterpret_cast<float2*>(&yp[ah][3][2 * sp]) = make_float2(a30, a31);
    __syncthreads();

    // ---- softmax: group g = ah owns t-row g; 128 threads handle s=L and s=L+128 ----
    {
        const int g = ah;
        const int L = sp;
        const int w2 = (tid >> 6) & 1;
        float yL = (yp[0][g][L]       + yp[1][g][L])       + (yp[2][g][L]       + yp[3][g][L]);
        float yH = (yp[0][g][L + 128] + yp[1][g][L + 128]) + (yp[2][g][L + 128] + yp[3][g][L + 128]);
        float mn = fminf(yL, yH);
        #pragma unroll
        for (int off = 1; off < 64; off <<= 1)
            mn = fminf(mn, __shfl_xor(mn, off));
        if ((tid & 63) == 0) redm[g][w2] = mn;
        __syncthreads();
        mn = fminf(redm[g][0], redm[g][1]);
        float eL = __builtin_amdgcn_exp2f(PS * (mn - yL));
        float eH = __builtin_amdgcn_exp2f(PS * (mn - yH));
        float sm = eL + eH;
        #pragma unroll
        for (int off = 1; off < 64; off <<= 1)
            sm += __shfl_xor(sm, off);
        if ((tid & 63) == 0) reds[g][w2] = sm;
        __syncthreads();
        sm = reds[g][0] + reds[g][1];
        float rs = __builtin_amdgcn_rcpf(sm);
        wlt[L][g]       = eL * rs;
        wlt[L + 128][g] = eH * rs;
    }
    __syncthreads();

    // ---- PV: thread owns d = tid, 4 t-rows ----
    {
        const int d = tid;
        const float* sop = &SO[(size_t)b * 256 * 512 + d];
        float c0 = 0.f, c1 = 0.f, c2 = 0.f, c3 = 0.f;
        for (int s0 = 0; s0 < 256; s0 += 4) {
            float so[4];
            #pragma unroll
            for (int u = 0; u < 4; ++u) so[u] = sop[(s0 + u) * 512];
            #pragma unroll
            for (int u = 0; u < 4; ++u) {
                float4 w4 = *reinterpret_cast<const float4*>(&wlt[s0 + u][0]);
                c0 = fmaf(w4.x, so[u], c0);
                c1 = fmaf(w4.y, so[u], c1);
                c2 = fmaf(w4.z, so[u], c2);
                c3 = fmaf(w4.w, so[u], c3);
            }
        }
        float* op = &out_cslot[((size_t)(b * 256 + t0)) * 512 + d];
        op[0] = c0; op[512] = c1; op[1024] = c2; op[1536] = c3;
    }

    // ---- intent: folded into blocks 0..7 (b == bid here) ----
    if (bid < 8) {
        __syncthreads();
        float sc = 0.f;
        if (tid < 256) {
            for (int nb = 0; nb < npart; ++nb) sc += ipart[nb * 2048 + b * 256 + tid];
            redI[tid] = sc;
        }
        __syncthreads();
        for (int off = 128; off > 0; off >>= 1) {
            if (tid < off) redI[tid] = fmaxf(redI[tid], redI[tid + off]);
            __syncthreads();
        }
        float mx = redI[0];
        __syncthreads();
        float e = 0.f;
        if (tid < 256) { e = __builtin_amdgcn_exp2f((sc - mx) * LOG2E); redI[tid] = e; }
        __syncthreads();
        for (int off = 128; off > 0; off >>= 1) {
            if (tid < off) redI[tid] += redI[tid + off];
            __syncthreads();
        }
        if (tid < 256) wlI[tid] = e * __builtin_amdgcn_rcpf(redI[0]);
        __syncthreads();
        const int d = tid;
        float c = 0.f;
        const float* sop = &SO[(size_t)b * 256 * 512 + d];
        for (int s0 = 0; s0 < 256; s0 += 4) {
            float so[4];
            #pragma unroll
            for (int u = 0; u < 4; ++u) so[u] = sop[(s0 + u) * 512];
            #pragma unroll
            for (int u = 0; u < 4; ++u) c = fmaf(wlI[s0 + u], so[u], c);
        }
        out_cint[(size_t)b * 512 + d] = c;
    }
}

extern "C" void kernel_launch(void* const* d_in, const int* in_sizes, int n_in,
                              void* d_out, int out_size, void* d_ws, size_t ws_size,
                              hipStream_t stream) {
    const float* SO  = (const float*)d_in[0];
    const float* FS  = (const float*)d_in[1];
    const float* IV  = (const float*)d_in[2];
    const float* Wih = (const float*)d_in[3];
    const float* bih = (const float*)d_in[4];
    const float* Wii = (const float*)d_in[5];
    const float* bii = (const float*)d_in[6];
    const float* SV  = (const float*)d_in[7];
    const float* Wsh = (const float*)d_in[8];
    const float* bsh = (const float*)d_in[9];
    const float* Wsi = (const float*)d_in[10];
    const float* bsi = (const float*)d_in[11];

    float* ws    = (float*)d_ws;
    float* EhT   = ws;                 // [8][512][256]  exp2'd   1,048,576 f
    float* Es    = ws + 1048576;       // [2048][512]    exp2'd   1,048,576 f
    float* ii    = ws + 2097152;       // [8][512]                4,096 f
    float* ipart = ws + 2101248;       // [16][2048]              32,768 f
    ushort* Ast  = (ushort*)(ws + 2134016);  // [2048][1024] bf16
    ushort* Wt   = (ushort*)(ws + 3182592);  // [1536][1024] bf16
    const size_t NEED = (size_t)3969024 * 4;

    float* out_cslot = (float*)d_out;
    float* out_cint  = out_cslot + BB * TT * DD;

    if (ws_size >= NEED) {
        prep<<<1808, 256, 0, stream>>>(SO, Ast, Wsh, Wsi, Wih, Wt, FS, Wii, bii, ii);
        gemm_mfma<<<dim3(32, 24), 256, 0, stream>>>(Ast, Wt, bsh, bsi, bih, ii, IV,
                                                    EhT, Es, ipart);
        k3_fused<<<512, 512, 0, stream>>>(SO, EhT, Es, SV, ipart, out_cslot, out_cint, 16);
    } else {
        k0_ii<<<dim3(BB, 2), 256, 0, stream>>>(FS, Wii, bii, ii);
        k1_gemm_old<<<dim3(32, 8, 3), 256, 0, stream>>>(SO, Wsh, bsh, Wsi, bsi, Wih, bih,
                                                        ii, IV, EhT, Es, ipart);
        k3_fused<<<512, 512, 0, stream>>>(SO, EhT, Es, SV, ipart, out_cslot, out_cint, 8);
    }
}

// Round 14
// 93.300 us; speedup vs baseline: 1.0085x; 1.0085x over previous
//
#include <hip/hip_runtime.h>

#define BB 8
#define TT 256
#define DD 512
#define AA 512

#define PS 2.8853900817779268f   // 2*log2(e)
#define LOG2E 1.4426950408889634f

typedef __attribute__((ext_vector_type(8))) short short8;
typedef __attribute__((ext_vector_type(4))) float f32x4;

#define AS1 __attribute__((address_space(1)))
#define AS3 __attribute__((address_space(3)))

__device__ __forceinline__ void gld16(const char* g, char* l) {
    __builtin_amdgcn_global_load_lds((const AS1 unsigned int*)g,
                                     (AS3 unsigned int*)l, 16, 0, 0);
}

__device__ __forceinline__ float fast_tanh(float x) {
    float e = __builtin_amdgcn_exp2f(x * PS);
    float r = __builtin_amdgcn_rcpf(1.0f + e);
    return fmaf(-2.0f, r, 1.0f);
}

__device__ __forceinline__ ushort f2bf(float x) {
    uint u = __float_as_uint(x);
    uint r = (u + 0x7fffu + ((u >> 16) & 1u)) >> 16;  // RNE
    return (ushort)r;
}
__device__ __forceinline__ float bf2f(ushort h) {
    return __uint_as_float(((uint)h) << 16);
}

#define ABYTE(k0) (((k0) < 1024 ? (k0) : (k0) - 1024) * 2)
#define BBYTE(k0) (((k0) < 512 ? (k0) : (k0) - 512) * 2)

// ---------------- prep: k0 (blocks 0..15) + conv_W (16..783) + conv_A (784..1807) --------
__global__ __launch_bounds__(256) void prep(const float* __restrict__ SO,
                                            ushort* __restrict__ Ast,
                                            const float* __restrict__ Wsh,
                                            const float* __restrict__ Wsi,
                                            const float* __restrict__ Wih,
                                            ushort* __restrict__ Wt,
                                            const float* __restrict__ fs_g,
                                            const float* __restrict__ Wii,
                                            const float* __restrict__ bii,
                                            float* __restrict__ ii) {
    const int bid = blockIdx.x;
    const int tid = threadIdx.x;
    __shared__ float T[32][33];
    __shared__ float fs[DD];

    if (bid < 16) {
        int b = bid >> 1, half = bid & 1;
        int a = half * 256 + tid;
        fs[tid]       = fs_g[b * DD + tid];
        fs[tid + 256] = fs_g[b * DD + tid + 256];
        __syncthreads();
        float acc = bii[a];
        #pragma unroll 8
        for (int d = 0; d < DD; ++d)
            acc = fmaf(fs[d], Wii[(size_t)d * AA + a], acc);
        ii[b * AA + a] = acc;
    } else if (bid < 784) {
        int lbid = bid - 16;
        int z = lbid >> 8;
        int rem = lbid & 255;
        const float* W = (z == 0) ? Wsh : (z == 1) ? Wsi : Wih;
        int k0 = (rem & 15) * 32, n0 = (rem >> 4) * 32;
        int tx = tid & 31, ty = tid >> 5;
        #pragma unroll
        for (int r = 0; r < 4; ++r) {
            int kl = ty * 4 + r;
            T[kl][tx] = W[(size_t)(k0 + kl) * 512 + n0 + tx];
        }
        __syncthreads();
        size_t nbase = (size_t)z * 512 + n0;
        #pragma unroll
        for (int r = 0; r < 4; ++r) {
            int nl = ty * 4 + r;
            float v = T[tx][nl];
            ushort hi = f2bf(v);
            ushort lo = f2bf(v - bf2f(hi));
            Wt[(nbase + nl) * 1024 + k0 + tx]       = hi;
            Wt[(nbase + nl) * 1024 + 512 + k0 + tx] = lo;
        }
    } else {
        int qid = (bid - 784) * 256 + tid;
        int m = qid >> 7;
        int k4 = (qid & 127) * 4;
        float4 v = *reinterpret_cast<const float4*>(&SO[(size_t)m * 512 + k4]);
        ushort4 hi, lo;
        hi.x = f2bf(v.x); lo.x = f2bf(v.x - bf2f(hi.x));
        hi.y = f2bf(v.y); lo.y = f2bf(v.y - bf2f(hi.y));
        hi.z = f2bf(v.z); lo.z = f2bf(v.z - bf2f(hi.z));
        hi.w = f2bf(v.w); lo.w = f2bf(v.w - bf2f(hi.w));
        *reinterpret_cast<ushort4*>(&Ast[(size_t)m * 1024 + k4])       = hi;
        *reinterpret_cast<ushort4*>(&Ast[(size_t)m * 1024 + 512 + k4]) = lo;
    }
}

// ---------------- gemm_mfma: 64x64 tile, BK=64, DMA staging via global_load_lds ----------
// LDS dest is LINEAR (wave-uniform base + lane*16); the swizzle is applied to the
// per-lane GLOBAL source ((q ^ row&7)*16), so LDS content == old layout; reads unchanged.
__global__ __launch_bounds__(256) void gemm_mfma(
    const ushort* __restrict__ Ast, const ushort* __restrict__ Wt,
    const float* __restrict__ bsh, const float* __restrict__ bsi,
    const float* __restrict__ bih,
    const float* __restrict__ ii, const float* __restrict__ iv,
    float* __restrict__ EhT, float* __restrict__ Es, float* __restrict__ ipart) {
    __shared__ __align__(16) ushort Al[2][64 * 64];
    __shared__ __align__(16) ushort Bl[2][64 * 64];
    const int tid = threadIdx.x;
    const int wave = tid >> 6, lane = tid & 63;
    const int wr = wave >> 1, wc = wave & 1;
    const int m0 = blockIdx.x * 64;
    const int by = blockIdx.y;
    const int n0 = by * 64;
    const int l15 = lane & 15, kb = lane >> 4;

    f32x4 acc[2][2] = {};

    const char* Ab = reinterpret_cast<const char*>(Ast);
    const char* Bb = reinterpret_cast<const char*>(Wt);
    char* AlB = reinterpret_cast<char*>(&Al[0][0]);
    char* BlB = reinterpret_cast<char*>(&Bl[0][0]);

    // DMA staging geometry: wave stages rows [wave*16, wave*16+16) of A and B.
    // chunk c in {0,1}: 8 rows x 128B = 1KB; lane l -> row base+ (l>>3), slot q=l&7.
    const int r8 = lane >> 3;           // 0..7
    const int qx = ((lane & 7) ^ r8) * 16;   // inverse-swizzled source slot
    const char* asrc0 = Ab + (size_t)(m0 + wave * 16 + 0 + r8) * 2048 + qx;
    const char* asrc1 = Ab + (size_t)(m0 + wave * 16 + 8 + r8) * 2048 + qx;
    const char* bsrc0 = Bb + (size_t)(n0 + wave * 16 + 0 + r8) * 2048 + qx;
    const char* bsrc1 = Bb + (size_t)(n0 + wave * 16 + 8 + r8) * 2048 + qx;
    const int ldsw = wave * 16 * 128;   // wave's dest base within a buffer

    #define STAGE(BUF, S) do {                                   \
        const int k0_ = (S) * 64;                                \
        const int ab_ = ABYTE(k0_), bb_ = BBYTE(k0_);            \
        char* Ad_ = AlB + (BUF) * 8192 + ldsw;                   \
        char* Bd_ = BlB + (BUF) * 8192 + ldsw;                   \
        gld16(asrc0 + ab_, Ad_);                                 \
        gld16(asrc1 + ab_, Ad_ + 1024);                          \
        gld16(bsrc0 + bb_, Bd_);                                 \
        gld16(bsrc1 + bb_, Bd_ + 1024);                          \
    } while (0)

    // frag read offsets (within one 8KB buffer) — same swizzle as before
    int aro[2][2], bro[2][2];
    #pragma unroll
    for (int i = 0; i < 2; ++i) {
        int ra = wr * 32 + i * 16 + l15;
        int rb = wc * 32 + i * 16 + l15;
        #pragma unroll
        for (int kk = 0; kk < 2; ++kk) {
            aro[kk][i] = ra * 128 + (((kk * 4 + kb) ^ (ra & 7)) * 16);
            bro[kk][i] = rb * 128 + (((kk * 4 + kb) ^ (rb & 7)) * 16);
        }
    }

    STAGE(0, 0);
    __syncthreads();

    #pragma unroll
    for (int it = 0; it < 24; ++it) {
        if (it + 1 < 24) STAGE((it + 1) & 1, it + 1);   // DMA overlaps MFMA below
        const char* Ac = AlB + (it & 1) * 8192;
        const char* Bc = BlB + (it & 1) * 8192;
        #pragma unroll
        for (int kk = 0; kk < 2; ++kk) {
            short8 af[2], bf[2];
            #pragma unroll
            for (int i = 0; i < 2; ++i) {
                af[i] = *reinterpret_cast<const short8*>(Ac + aro[kk][i]);
                bf[i] = *reinterpret_cast<const short8*>(Bc + bro[kk][i]);
            }
            #pragma unroll
            for (int i = 0; i < 2; ++i)
                #pragma unroll
                for (int j = 0; j < 2; ++j)
                    acc[i][j] = __builtin_amdgcn_mfma_f32_16x16x32_bf16(
                        af[i], bf[j], acc[i][j], 0, 0, 0);
        }
        __syncthreads();
    }

    const int b = m0 >> 8;
    if (by < 8) {
        #pragma unroll
        for (int i = 0; i < 2; ++i) {
            int t0 = (m0 & 255) + wr * 32 + i * 16 + kb * 4;
            #pragma unroll
            for (int j = 0; j < 2; ++j) {
                int n = n0 + wc * 32 + j * 16 + l15;
                float bbv = bsh[n];
                float4 v;
                v.x = __builtin_amdgcn_exp2f((acc[i][j][0] + bbv) * PS);
                v.y = __builtin_amdgcn_exp2f((acc[i][j][1] + bbv) * PS);
                v.z = __builtin_amdgcn_exp2f((acc[i][j][2] + bbv) * PS);
                v.w = __builtin_amdgcn_exp2f((acc[i][j][3] + bbv) * PS);
                *reinterpret_cast<float4*>(&EhT[((size_t)b * 512 + n) * 256 + t0]) = v;
            }
        }
    } else if (by < 16) {
        #pragma unroll
        for (int i = 0; i < 2; ++i) {
            #pragma unroll
            for (int j = 0; j < 2; ++j) {
                int n = n0 - 512 + wc * 32 + j * 16 + l15;
                float bbv = bsi[n];
                #pragma unroll
                for (int r = 0; r < 4; ++r) {
                    int m = m0 + wr * 32 + i * 16 + kb * 4 + r;
                    Es[(size_t)m * 512 + n] = __builtin_amdgcn_exp2f((acc[i][j][r] + bbv) * PS);
                }
            }
        }
    } else {
        int slot = (by - 16) * 2 + wc;
        #pragma unroll
        for (int i = 0; i < 2; ++i) {
            float p0 = 0.f, p1 = 0.f, p2 = 0.f, p3 = 0.f;
            #pragma unroll
            for (int j = 0; j < 2; ++j) {
                int n = n0 - 1024 + wc * 32 + j * 16 + l15;
                float add = bih[n] + ii[b * 512 + n];
                float w = iv[n];
                p0 = fmaf(w, fast_tanh(acc[i][j][0] + add), p0);
                p1 = fmaf(w, fast_tanh(acc[i][j][1] + add), p1);
                p2 = fmaf(w, fast_tanh(acc[i][j][2] + add), p2);
                p3 = fmaf(w, fast_tanh(acc[i][j][3] + add), p3);
            }
            #pragma unroll
            for (int off = 1; off < 16; off <<= 1) {
                p0 += __shfl_xor(p0, off);
                p1 += __shfl_xor(p1, off);
                p2 += __shfl_xor(p2, off);
                p3 += __shfl_xor(p3, off);
            }
            int mb = m0 + wr * 32 + i * 16 + kb * 4;
            if (l15 == 0) ipart[slot * 2048 + mb + 0] = p0;
            if (l15 == 1) ipart[slot * 2048 + mb + 1] = p1;
            if (l15 == 2) ipart[slot * 2048 + mb + 2] = p2;
            if (l15 == 3) ipart[slot * 2048 + mb + 3] = p3;
        }
    }
}

// ---------------- fallback fp32 GEMM path ----------------
#define TS 64
#define KS 16
#define LPAD 72

__global__ __launch_bounds__(256) void k0_ii(const float* __restrict__ fs_g,
                                             const float* __restrict__ Wii,
                                             const float* __restrict__ bii,
                                             float* __restrict__ ii) {
    int b = blockIdx.x, tid = threadIdx.x;
    int a = blockIdx.y * 256 + tid;
    __shared__ float fs[DD];
    fs[tid]       = fs_g[b * DD + tid];
    fs[tid + 256] = fs_g[b * DD + tid + 256];
    __syncthreads();
    float acc = bii[a];
    #pragma unroll 8
    for (int d = 0; d < DD; ++d)
        acc = fmaf(fs[d], Wii[(size_t)d * AA + a], acc);
    ii[b * AA + a] = acc;
}

__global__ __launch_bounds__(256) void k1_gemm_old(
    const float* __restrict__ SO,
    const float* __restrict__ Wsh, const float* __restrict__ bsh,
    const float* __restrict__ Wsi, const float* __restrict__ bsi,
    const float* __restrict__ Wih, const float* __restrict__ bih,
    const float* __restrict__ ii, const float* __restrict__ iv,
    float* __restrict__ EhT, float* __restrict__ Es, float* __restrict__ ipart) {
    const int mode = blockIdx.z;
    const float* W;
    const float* bias;
    if (mode == 0)      { W = Wsh; bias = bsh; }
    else if (mode == 1) { W = Wsi; bias = bsi; }
    else                { W = Wih; bias = bih; }

    const int m0 = blockIdx.x * TS;
    const int n0 = blockIdx.y * TS;
    const int tid = threadIdx.x;
    const int tx = tid & 15, ty = tid >> 4;

    __shared__ __align__(16) float As[KS][LPAD];
    __shared__ __align__(16) float Bs[KS][LPAD];
    __shared__ __align__(16) float Cs[TS][LPAD];

    float acc[4][4] = {};
    const int arow = tid >> 2;
    const int akc  = (tid & 3) * 4;
    const int brw  = tid >> 4;
    const int bnc  = (tid & 15) * 4;

    for (int k0 = 0; k0 < DD; k0 += KS) {
        float4 av = *reinterpret_cast<const float4*>(&SO[(m0 + arow) * DD + k0 + akc]);
        As[akc + 0][arow] = av.x;
        As[akc + 1][arow] = av.y;
        As[akc + 2][arow] = av.z;
        As[akc + 3][arow] = av.w;
        float4 bv = *reinterpret_cast<const float4*>(&W[(k0 + brw) * AA + n0 + bnc]);
        *reinterpret_cast<float4*>(&Bs[brw][bnc]) = bv;
        __syncthreads();
        #pragma unroll
        for (int kk = 0; kk < KS; ++kk) {
            float4 a4 = *reinterpret_cast<const float4*>(&As[kk][ty * 4]);
            float4 b4 = *reinterpret_cast<const float4*>(&Bs[kk][tx * 4]);
            float av_[4] = {a4.x, a4.y, a4.z, a4.w};
            float bv_[4] = {b4.x, b4.y, b4.z, b4.w};
            #pragma unroll
            for (int i = 0; i < 4; ++i)
                #pragma unroll
                for (int j = 0; j < 4; ++j)
                    acc[i][j] = fmaf(av_[i], bv_[j], acc[i][j]);
        }
        __syncthreads();
    }

    if (mode == 1) {
        #pragma unroll
        for (int i = 0; i < 4; ++i) {
            int m = m0 + ty * 4 + i;
            float4 v;
            v.x = __builtin_amdgcn_exp2f((acc[i][0] + bias[n0 + tx * 4 + 0]) * PS);
            v.y = __builtin_amdgcn_exp2f((acc[i][1] + bias[n0 + tx * 4 + 1]) * PS);
            v.z = __builtin_amdgcn_exp2f((acc[i][2] + bias[n0 + tx * 4 + 2]) * PS);
            v.w = __builtin_amdgcn_exp2f((acc[i][3] + bias[n0 + tx * 4 + 3]) * PS);
            *reinterpret_cast<float4*>(&Es[(size_t)m * AA + n0 + tx * 4]) = v;
        }
    } else if (mode == 0) {
        #pragma unroll
        for (int i = 0; i < 4; ++i)
            #pragma unroll
            for (int j = 0; j < 4; ++j)
                Cs[tx * 4 + j][ty * 4 + i] =
                    __builtin_amdgcn_exp2f((acc[i][j] + bias[n0 + tx * 4 + j]) * PS);
        __syncthreads();
        int row = tid >> 2, part = tid & 3;
        int bb = m0 >> 8;
        int tstart = (m0 & 255) + part * 16;
        float* dst = &EhT[bb * (AA * TT) + (n0 + row) * TT + tstart];
        #pragma unroll
        for (int q = 0; q < 4; ++q) {
            float4 v = *reinterpret_cast<const float4*>(&Cs[row][part * 16 + q * 4]);
            *reinterpret_cast<float4*>(&dst[q * 4]) = v;
        }
    } else {
        int bb = m0 >> 8;
        #pragma unroll
        for (int i = 0; i < 4; ++i) {
            float p = 0.f;
            #pragma unroll
            for (int j = 0; j < 4; ++j) {
                int n = n0 + tx * 4 + j;
                float x = acc[i][j] + bias[n] + ii[bb * AA + n];
                p = fmaf(iv[n], fast_tanh(x), p);
            }
            Cs[ty * 4 + i][tx] = p;
        }
        __syncthreads();
        if (tid < 64) {
            float s = 0.f;
            #pragma unroll
            for (int k = 0; k < 16; ++k) s += Cs[tid][k];
            ipart[blockIdx.y * 2048 + m0 + tid] = s;
        }
    }
}

// ---------------- k3_fused: round-12 exact (pairwise rcp-combine, best 45.5us) -----------
__global__ __launch_bounds__(512) void k3_fused(const float* __restrict__ SO,
                                                const float* __restrict__ EhT,
                                                const float* __restrict__ Es,
                                                const float* __restrict__ sv_g,
                                                const float* __restrict__ ipart,
                                                float* __restrict__ out_cslot,
                                                float* __restrict__ out_cint,
                                                int npart) {
    const int bid = blockIdx.x;
    const int tid = threadIdx.x;

    __shared__ __align__(16) float est[512][4];   // [a][q]
    __shared__ __align__(16) float sv[512];
    __shared__ __align__(8)  float yp[4][4][256]; // [ah][q][s]
    __shared__ __align__(16) float wlt[256][4];
    __shared__ float redm[4][2];
    __shared__ float reds[4][2];
    __shared__ float redI[256];
    __shared__ float wlI[256];

    const int b = bid & 7;          // XCD-affine
    const int t0 = (bid >> 3) * 4;
    const int sp = tid & 127;       // s-pair index: s = 2*sp, 2*sp+1
    const int ah = tid >> 7;        // 0..3, a-quarter
    const int abase = ah * 128;

    // stage est (transposed gather) + sv
    {
        const float* esrc = &Es[(size_t)(b * 256 + t0) * 512];
        #pragma unroll
        for (int i = tid; i < 2048; i += 512) est[i & 511][i >> 9] = esrc[i];
        sv[tid] = sv_g[tid];
    }
    __syncthreads();

    // ---- score: 128 a x 4 t x 2 s per thread; a-pairs share one rcp ----
    const float* hp = &EhT[((size_t)b * 512 + abase) * 256 + 2 * sp];
    float a00=0.f,a01=0.f,a10=0.f,a11=0.f,a20=0.f,a21=0.f,a30=0.f,a31=0.f;
    float2 h0[4], h1[4];
    #pragma unroll
    for (int u = 0; u < 4; ++u)
        h0[u] = *reinterpret_cast<const float2*>(&hp[u * 256]);

    // one (t) slice of a pair: two s-values, shared va/vb
    #define PAIRT(HA, HB, E1, E2, VA, VB, ACC0, ACC1) do {                         \
        float d1x = fmaf((HA).x, (E1), 1.f);                                       \
        float d2x = fmaf((HB).x, (E2), 1.f);                                       \
        ACC0 = fmaf(fmaf((VA), d2x, (VB) * d1x),                                   \
                    __builtin_amdgcn_rcpf(d1x * d2x), ACC0);                       \
        float d1y = fmaf((HA).y, (E1), 1.f);                                       \
        float d2y = fmaf((HB).y, (E2), 1.f);                                       \
        ACC1 = fmaf(fmaf((VA), d2y, (VB) * d1y),                                   \
                    __builtin_amdgcn_rcpf(d1y * d2y), ACC1);                       \
    } while (0)

    #define SCOREP(A0, H) do {                                                     \
        float4 v4 = *reinterpret_cast<const float4*>(&sv[abase + (A0)]);           \
        float4 e0 = *reinterpret_cast<const float4*>(&est[abase + (A0) + 0][0]);   \
        float4 e1 = *reinterpret_cast<const float4*>(&est[abase + (A0) + 1][0]);   \
        float4 e2 = *reinterpret_cast<const float4*>(&est[abase + (A0) + 2][0]);   \
        float4 e3 = *reinterpret_cast<const float4*>(&est[abase + (A0) + 3][0]);   \
        PAIRT(H[0], H[1], e0.x, e1.x, v4.x, v4.y, a00, a01);                       \
        PAIRT(H[0], H[1], e0.y, e1.y, v4.x, v4.y, a10, a11);                       \
        PAIRT(H[0], H[1], e0.z, e1.z, v4.x, v4.y, a20, a21);                       \
        PAIRT(H[0], H[1], e0.w, e1.w, v4.x, v4.y, a30, a31);                       \
        PAIRT(H[2], H[3], e2.x, e3.x, v4.z, v4.w, a00, a01);                       \
        PAIRT(H[2], H[3], e2.y, e3.y, v4.z, v4.w, a10, a11);                       \
        PAIRT(H[2], H[3], e2.z, e3.z, v4.z, v4.w, a20, a21);                       \
        PAIRT(H[2], H[3], e2.w, e3.w, v4.z, v4.w, a30, a31);                       \
    } while (0)

    for (int a0 = 0; a0 < 128; a0 += 8) {
        #pragma unroll
        for (int u = 0; u < 4; ++u)
            h1[u] = *reinterpret_cast<const float2*>(&hp[(a0 + 4 + u) * 256]);
        SCOREP(a0, h0);
        #pragma unroll
        for (int u = 0; u < 4; ++u)   // over-read at a0=120 stays inside ws (Es region)
            h0[u] = *reinterpret_cast<const float2*>(&hp[(a0 + 8 + u) * 256]);
        SCOREP(a0 + 4, h1);
    }

    *reinterpret_cast<float2*>(&yp[ah][0][2 * sp]) = make_float2(a00, a01);
    *reinterpret_cast<float2*>(&yp[ah][1][2 * sp]) = make_float2(a10, a11);
    *reinterpret_cast<float2*>(&yp[ah][2][2 * sp]) = make_float2(a20, a21);
    *reinterpret_cast<float2*>(&yp[ah][3][2 * sp]) = make_float2(a30, a31);
    __syncthreads();

    // ---- softmax: group g = ah owns t-row g; 128 threads handle s=L and s=L+128 ----
    {
        const int g = ah;
        const int L = sp;
        const int w2 = (tid >> 6) & 1;
        float yL = (yp[0][g][L]       + yp[1][g][L])       + (yp[2][g][L]       + yp[3][g][L]);
        float yH = (yp[0][g][L + 128] + yp[1][g][L + 128]) + (yp[2][g][L + 128] + yp[3][g][L + 128]);
        float mn = fminf(yL, yH);
        #pragma unroll
        for (int off = 1; off < 64; off <<= 1)
            mn = fminf(mn, __shfl_xor(mn, off));
        if ((tid & 63) == 0) redm[g][w2] = mn;
        __syncthreads();
        mn = fminf(redm[g][0], redm[g][1]);
        float eL = __builtin_amdgcn_exp2f(PS * (mn - yL));
        float eH = __builtin_amdgcn_exp2f(PS * (mn - yH));
        float sm = eL + eH;
        #pragma unroll
        for (int off = 1; off < 64; off <<= 1)
            sm += __shfl_xor(sm, off);
        if ((tid & 63) == 0) reds[g][w2] = sm;
        __syncthreads();
        sm = reds[g][0] + reds[g][1];
        float rs = __builtin_amdgcn_rcpf(sm);
        wlt[L][g]       = eL * rs;
        wlt[L + 128][g] = eH * rs;
    }
    __syncthreads();

    // ---- PV: thread owns d = tid, 4 t-rows ----
    {
        const int d = tid;
        const float* sop = &SO[(size_t)b * 256 * 512 + d];
        float c0 = 0.f, c1 = 0.f, c2 = 0.f, c3 = 0.f;
        for (int s0 = 0; s0 < 256; s0 += 4) {
            float so[4];
            #pragma unroll
            for (int u = 0; u < 4; ++u) so[u] = sop[(s0 + u) * 512];
            #pragma unroll
            for (int u = 0; u < 4; ++u) {
                float4 w4 = *reinterpret_cast<const float4*>(&wlt[s0 + u][0]);
                c0 = fmaf(w4.x, so[u], c0);
                c1 = fmaf(w4.y, so[u], c1);
                c2 = fmaf(w4.z, so[u], c2);
                c3 = fmaf(w4.w, so[u], c3);
            }
        }
        float* op = &out_cslot[((size_t)(b * 256 + t0)) * 512 + d];
        op[0] = c0; op[512] = c1; op[1024] = c2; op[1536] = c3;
    }

    // ---- intent: folded into blocks 0..7 (b == bid here) ----
    if (bid < 8) {
        __syncthreads();
        float sc = 0.f;
        if (tid < 256) {
            for (int nb = 0; nb < npart; ++nb) sc += ipart[nb * 2048 + b * 256 + tid];
            redI[tid] = sc;
        }
        __syncthreads();
        for (int off = 128; off > 0; off >>= 1) {
            if (tid < off) redI[tid] = fmaxf(redI[tid], redI[tid + off]);
            __syncthreads();
        }
        float mx = redI[0];
        __syncthreads();
        float e = 0.f;
        if (tid < 256) { e = __builtin_amdgcn_exp2f((sc - mx) * LOG2E); redI[tid] = e; }
        __syncthreads();
        for (int off = 128; off > 0; off >>= 1) {
            if (tid < off) redI[tid] += redI[tid + off];
            __syncthreads();
        }
        if (tid < 256) wlI[tid] = e * __builtin_amdgcn_rcpf(redI[0]);
        __syncthreads();
        const int d = tid;
        float c = 0.f;
        const float* sop = &SO[(size_t)b * 256 * 512 + d];
        for (int s0 = 0; s0 < 256; s0 += 4) {
            float so[4];
            #pragma unroll
            for (int u = 0; u < 4; ++u) so[u] = sop[(s0 + u) * 512];
            #pragma unroll
            for (int u = 0; u < 4; ++u) c = fmaf(wlI[s0 + u], so[u], c);
        }
        out_cint[(size_t)b * 512 + d] = c;
    }
}

extern "C" void kernel_launch(void* const* d_in, const int* in_sizes, int n_in,
                              void* d_out, int out_size, void* d_ws, size_t ws_size,
                              hipStream_t stream) {
    const float* SO  = (const float*)d_in[0];
    const float* FS  = (const float*)d_in[1];
    const float* IV  = (const float*)d_in[2];
    const float* Wih = (const float*)d_in[3];
    const float* bih = (const float*)d_in[4];
    const float* Wii = (const float*)d_in[5];
    const float* bii = (const float*)d_in[6];
    const float* SV  = (const float*)d_in[7];
    const float* Wsh = (const float*)d_in[8];
    const float* bsh = (const float*)d_in[9];
    const float* Wsi = (const float*)d_in[10];
    const float* bsi = (const float*)d_in[11];

    float* ws    = (float*)d_ws;
    float* EhT   = ws;                 // [8][512][256]  exp2'd   1,048,576 f
    float* Es    = ws + 1048576;       // [2048][512]    exp2'd   1,048,576 f
    float* ii    = ws + 2097152;       // [8][512]                4,096 f
    float* ipart = ws + 2101248;       // [16][2048]              32,768 f
    ushort* Ast  = (ushort*)(ws + 2134016);  // [2048][1024] bf16
    ushort* Wt   = (ushort*)(ws + 3182592);  // [1536][1024] bf16
    const size_t NEED = (size_t)3969024 * 4;

    float* out_cslot = (float*)d_out;
    float* out_cint  = out_cslot + BB * TT * DD;

    if (ws_size >= NEED) {
        prep<<<1808, 256, 0, stream>>>(SO, Ast, Wsh, Wsi, Wih, Wt, FS, Wii, bii, ii);
        gemm_mfma<<<dim3(32, 24), 256, 0, stream>>>(Ast, Wt, bsh, bsi, bih, ii, IV,
                                                    EhT, Es, ipart);
        k3_fused<<<512, 512, 0, stream>>>(SO, EhT, Es, SV, ipart, out_cslot, out_cint, 16);
    } else {
        k0_ii<<<dim3(BB, 2), 256, 0, stream>>>(FS, Wii, bii, ii);
        k1_gemm_old<<<dim3(32, 8, 3), 256, 0, stream>>>(SO, Wsh, bsh, Wsi, bsi, Wih, bih,
                                                        ii, IV, EhT, Es, ipart);
        k3_fused<<<512, 512, 0, stream>>>(SO, EhT, Es, SV, ipart, out_cslot, out_cint, 8);
    }
}

// Round 15
// 90.703 us; speedup vs baseline: 1.0374x; 1.0286x over previous
//
#include <hip/hip_runtime.h>

#define BB 8
#define TT 256
#define DD 512
#define AA 512

#define PS 2.8853900817779268f   // 2*log2(e)
#define LOG2E 1.4426950408889634f

typedef __attribute__((ext_vector_type(8))) short short8;
typedef __attribute__((ext_vector_type(4))) float f32x4;

__device__ __forceinline__ float fast_tanh(float x) {
    float e = __builtin_amdgcn_exp2f(x * PS);
    float r = __builtin_amdgcn_rcpf(1.0f + e);
    return fmaf(-2.0f, r, 1.0f);
}

__device__ __forceinline__ ushort f2bf(float x) {
    uint u = __float_as_uint(x);
    uint r = (u + 0x7fffu + ((u >> 16) & 1u)) >> 16;  // RNE
    return (ushort)r;
}
__device__ __forceinline__ float bf2f(ushort h) {
    return __uint_as_float(((uint)h) << 16);
}

#define ABYTE(k0) (((k0) < 1024 ? (k0) : (k0) - 1024) * 2)
#define BBYTE(k0) (((k0) < 512 ? (k0) : (k0) - 512) * 2)

// ---------------- prep: k0 (blocks 0..15) + conv_W (16..783) + conv_A (784..1807) --------
__global__ __launch_bounds__(256) void prep(const float* __restrict__ SO,
                                            ushort* __restrict__ Ast,
                                            const float* __restrict__ Wsh,
                                            const float* __restrict__ Wsi,
                                            const float* __restrict__ Wih,
                                            ushort* __restrict__ Wt,
                                            const float* __restrict__ fs_g,
                                            const float* __restrict__ Wii,
                                            const float* __restrict__ bii,
                                            float* __restrict__ ii) {
    const int bid = blockIdx.x;
    const int tid = threadIdx.x;
    __shared__ float T[32][33];
    __shared__ float fs[DD];

    if (bid < 16) {
        int b = bid >> 1, half = bid & 1;
        int a = half * 256 + tid;
        fs[tid]       = fs_g[b * DD + tid];
        fs[tid + 256] = fs_g[b * DD + tid + 256];
        __syncthreads();
        float acc = bii[a];
        #pragma unroll 8
        for (int d = 0; d < DD; ++d)
            acc = fmaf(fs[d], Wii[(size_t)d * AA + a], acc);
        ii[b * AA + a] = acc;
    } else if (bid < 784) {
        int lbid = bid - 16;
        int z = lbid >> 8;
        int rem = lbid & 255;
        const float* W = (z == 0) ? Wsh : (z == 1) ? Wsi : Wih;
        int k0 = (rem & 15) * 32, n0 = (rem >> 4) * 32;
        int tx = tid & 31, ty = tid >> 5;
        #pragma unroll
        for (int r = 0; r < 4; ++r) {
            int kl = ty * 4 + r;
            T[kl][tx] = W[(size_t)(k0 + kl) * 512 + n0 + tx];
        }
        __syncthreads();
        size_t nbase = (size_t)z * 512 + n0;
        #pragma unroll
        for (int r = 0; r < 4; ++r) {
            int nl = ty * 4 + r;
            float v = T[tx][nl];
            ushort hi = f2bf(v);
            ushort lo = f2bf(v - bf2f(hi));
            Wt[(nbase + nl) * 1024 + k0 + tx]       = hi;
            Wt[(nbase + nl) * 1024 + 512 + k0 + tx] = lo;
        }
    } else {
        int qid = (bid - 784) * 256 + tid;
        int m = qid >> 7;
        int k4 = (qid & 127) * 4;
        float4 v = *reinterpret_cast<const float4*>(&SO[(size_t)m * 512 + k4]);
        ushort4 hi, lo;
        hi.x = f2bf(v.x); lo.x = f2bf(v.x - bf2f(hi.x));
        hi.y = f2bf(v.y); lo.y = f2bf(v.y - bf2f(hi.y));
        hi.z = f2bf(v.z); lo.z = f2bf(v.z - bf2f(hi.z));
        hi.w = f2bf(v.w); lo.w = f2bf(v.w - bf2f(hi.w));
        *reinterpret_cast<ushort4*>(&Ast[(size_t)m * 1024 + k4])       = hi;
        *reinterpret_cast<ushort4*>(&Ast[(size_t)m * 1024 + 512 + k4]) = lo;
    }
}

// ---------------- gemm_mfma: 64x64 tile, BK=64, LDS dbuf + depth-2 reg prefetch ----------
__global__ __launch_bounds__(256) void gemm_mfma(
    const ushort* __restrict__ Ast, const ushort* __restrict__ Wt,
    const float* __restrict__ bsh, const float* __restrict__ bsi,
    const float* __restrict__ bih,
    const float* __restrict__ ii, const float* __restrict__ iv,
    float* __restrict__ EhT, float* __restrict__ Es, float* __restrict__ ipart) {
    __shared__ __align__(16) ushort Al[2][64 * 64];
    __shared__ __align__(16) ushort Bl[2][64 * 64];
    const int tid = threadIdx.x;
    const int wave = tid >> 6, lane = tid & 63;
    const int wr = wave >> 1, wc = wave & 1;
    const int m0 = blockIdx.x * 64;
    const int by = blockIdx.y;
    const int n0 = by * 64;
    const int l15 = lane & 15, kb = lane >> 4;

    f32x4 acc[2][2] = {};

    const char* Ab = reinterpret_cast<const char*>(Ast);
    const char* Bb = reinterpret_cast<const char*>(Wt);
    char* AlB = reinterpret_cast<char*>(&Al[0][0]);
    char* BlB = reinterpret_cast<char*>(&Bl[0][0]);

    const int srow = tid >> 2, sslot = tid & 3;
    const int lw0 = srow * 128 + (((sslot    ) ^ (srow & 7)) * 16);
    const int lw1 = srow * 128 + (((sslot + 4) ^ (srow & 7)) * 16);
    const char* agp = Ab + (size_t)(m0 + srow) * 2048 + sslot * 16;
    const char* bgp = Bb + (size_t)(n0 + srow) * 2048 + sslot * 16;

    int aro[2][2], bro[2][2];
    #pragma unroll
    for (int i = 0; i < 2; ++i) {
        int ra = wr * 32 + i * 16 + l15;
        int rb = wc * 32 + i * 16 + l15;
        #pragma unroll
        for (int kk = 0; kk < 2; ++kk) {
            aro[kk][i] = ra * 128 + (((kk * 4 + kb) ^ (ra & 7)) * 16);
            bro[kk][i] = rb * 128 + (((kk * 4 + kb) ^ (rb & 7)) * 16);
        }
    }

    #define GLOAD4(H, S) do {                                        \
        const int k0_ = (S) * 64;                                    \
        const int ab_ = ABYTE(k0_), bb_ = BBYTE(k0_);                \
        H[0] = *reinterpret_cast<const short8*>(agp + ab_);          \
        H[1] = *reinterpret_cast<const short8*>(agp + ab_ + 64);     \
        H[2] = *reinterpret_cast<const short8*>(bgp + bb_);          \
        H[3] = *reinterpret_cast<const short8*>(bgp + bb_ + 64);     \
    } while (0)

    #define STLDS(BUF, H) do {                                       \
        char* An_ = AlB + (BUF) * 8192;                              \
        char* Bn_ = BlB + (BUF) * 8192;                              \
        *reinterpret_cast<short8*>(An_ + lw0) = H[0];                \
        *reinterpret_cast<short8*>(An_ + lw1) = H[1];                \
        *reinterpret_cast<short8*>(Bn_ + lw0) = H[2];                \
        *reinterpret_cast<short8*>(Bn_ + lw1) = H[3];                \
    } while (0)

    short8 hld[2][4];
    GLOAD4(hld[0], 0);
    STLDS(0, hld[0]);
    GLOAD4(hld[1], 1);
    __syncthreads();

    #pragma unroll
    for (int it = 0; it < 24; ++it) {
        if (it + 2 < 24) GLOAD4(hld[it & 1], it + 2);
        const char* Ac = AlB + (it & 1) * 8192;
        const char* Bc = BlB + (it & 1) * 8192;
        #pragma unroll
        for (int kk = 0; kk < 2; ++kk) {
            short8 af[2], bf[2];
            #pragma unroll
            for (int i = 0; i < 2; ++i) {
                af[i] = *reinterpret_cast<const short8*>(Ac + aro[kk][i]);
                bf[i] = *reinterpret_cast<const short8*>(Bc + bro[kk][i]);
            }
            #pragma unroll
            for (int i = 0; i < 2; ++i)
                #pragma unroll
                for (int j = 0; j < 2; ++j)
                    acc[i][j] = __builtin_amdgcn_mfma_f32_16x16x32_bf16(
                        af[i], bf[j], acc[i][j], 0, 0, 0);
        }
        if (it + 1 < 24) STLDS((it + 1) & 1, hld[(it + 1) & 1]);
        __syncthreads();
    }

    const int b = m0 >> 8;
    if (by < 8) {
        #pragma unroll
        for (int i = 0; i < 2; ++i) {
            int t0 = (m0 & 255) + wr * 32 + i * 16 + kb * 4;
            #pragma unroll
            for (int j = 0; j < 2; ++j) {
                int n = n0 + wc * 32 + j * 16 + l15;
                float bbv = bsh[n];
                float4 v;
                v.x = __builtin_amdgcn_exp2f((acc[i][j][0] + bbv) * PS);
                v.y = __builtin_amdgcn_exp2f((acc[i][j][1] + bbv) * PS);
                v.z = __builtin_amdgcn_exp2f((acc[i][j][2] + bbv) * PS);
                v.w = __builtin_amdgcn_exp2f((acc[i][j][3] + bbv) * PS);
                *reinterpret_cast<float4*>(&EhT[((size_t)b * 512 + n) * 256 + t0]) = v;
            }
        }
    } else if (by < 16) {
        #pragma unroll
        for (int i = 0; i < 2; ++i) {
            #pragma unroll
            for (int j = 0; j < 2; ++j) {
                int n = n0 - 512 + wc * 32 + j * 16 + l15;
                float bbv = bsi[n];
                #pragma unroll
                for (int r = 0; r < 4; ++r) {
                    int m = m0 + wr * 32 + i * 16 + kb * 4 + r;
                    Es[(size_t)m * 512 + n] = __builtin_amdgcn_exp2f((acc[i][j][r] + bbv) * PS);
                }
            }
        }
    } else {
        int slot = (by - 16) * 2 + wc;
        #pragma unroll
        for (int i = 0; i < 2; ++i) {
            float p0 = 0.f, p1 = 0.f, p2 = 0.f, p3 = 0.f;
            #pragma unroll
            for (int j = 0; j < 2; ++j) {
                int n = n0 - 1024 + wc * 32 + j * 16 + l15;
                float add = bih[n] + ii[b * 512 + n];
                float w = iv[n];
                p0 = fmaf(w, fast_tanh(acc[i][j][0] + add), p0);
                p1 = fmaf(w, fast_tanh(acc[i][j][1] + add), p1);
                p2 = fmaf(w, fast_tanh(acc[i][j][2] + add), p2);
                p3 = fmaf(w, fast_tanh(acc[i][j][3] + add), p3);
            }
            #pragma unroll
            for (int off = 1; off < 16; off <<= 1) {
                p0 += __shfl_xor(p0, off);
                p1 += __shfl_xor(p1, off);
                p2 += __shfl_xor(p2, off);
                p3 += __shfl_xor(p3, off);
            }
            int mb = m0 + wr * 32 + i * 16 + kb * 4;
            if (l15 == 0) ipart[slot * 2048 + mb + 0] = p0;
            if (l15 == 1) ipart[slot * 2048 + mb + 1] = p1;
            if (l15 == 2) ipart[slot * 2048 + mb + 2] = p2;
            if (l15 == 3) ipart[slot * 2048 + mb + 3] = p3;
        }
    }
}

// ---------------- fallback fp32 GEMM path ----------------
#define TS 64
#define KS 16
#define LPAD 72

__global__ __launch_bounds__(256) void k0_ii(const float* __restrict__ fs_g,
                                             const float* __restrict__ Wii,
                                             const float* __restrict__ bii,
                                             float* __restrict__ ii) {
    int b = blockIdx.x, tid = threadIdx.x;
    int a = blockIdx.y * 256 + tid;
    __shared__ float fs[DD];
    fs[tid]       = fs_g[b * DD + tid];
    fs[tid + 256] = fs_g[b * DD + tid + 256];
    __syncthreads();
    float acc = bii[a];
    #pragma unroll 8
    for (int d = 0; d < DD; ++d)
        acc = fmaf(fs[d], Wii[(size_t)d * AA + a], acc);
    ii[b * AA + a] = acc;
}

__global__ __launch_bounds__(256) void k1_gemm_old(
    const float* __restrict__ SO,
    const float* __restrict__ Wsh, const float* __restrict__ bsh,
    const float* __restrict__ Wsi, const float* __restrict__ bsi,
    const float* __restrict__ Wih, const float* __restrict__ bih,
    const float* __restrict__ ii, const float* __restrict__ iv,
    float* __restrict__ EhT, float* __restrict__ Es, float* __restrict__ ipart) {
    const int mode = blockIdx.z;
    const float* W;
    const float* bias;
    if (mode == 0)      { W = Wsh; bias = bsh; }
    else if (mode == 1) { W = Wsi; bias = bsi; }
    else                { W = Wih; bias = bih; }

    const int m0 = blockIdx.x * TS;
    const int n0 = blockIdx.y * TS;
    const int tid = threadIdx.x;
    const int tx = tid & 15, ty = tid >> 4;

    __shared__ __align__(16) float As[KS][LPAD];
    __shared__ __align__(16) float Bs[KS][LPAD];
    __shared__ __align__(16) float Cs[TS][LPAD];

    float acc[4][4] = {};
    const int arow = tid >> 2;
    const int akc  = (tid & 3) * 4;
    const int brw  = tid >> 4;
    const int bnc  = (tid & 15) * 4;

    for (int k0 = 0; k0 < DD; k0 += KS) {
        float4 av = *reinterpret_cast<const float4*>(&SO[(m0 + arow) * DD + k0 + akc]);
        As[akc + 0][arow] = av.x;
        As[akc + 1][arow] = av.y;
        As[akc + 2][arow] = av.z;
        As[akc + 3][arow] = av.w;
        float4 bv = *reinterpret_cast<const float4*>(&W[(k0 + brw) * AA + n0 + bnc]);
        *reinterpret_cast<float4*>(&Bs[brw][bnc]) = bv;
        __syncthreads();
        #pragma unroll
        for (int kk = 0; kk < KS; ++kk) {
            float4 a4 = *reinterpret_cast<const float4*>(&As[kk][ty * 4]);
            float4 b4 = *reinterpret_cast<const float4*>(&Bs[kk][tx * 4]);
            float av_[4] = {a4.x, a4.y, a4.z, a4.w};
            float bv_[4] = {b4.x, b4.y, b4.z, b4.w};
            #pragma unroll
            for (int i = 0; i < 4; ++i)
                #pragma unroll
                for (int j = 0; j < 4; ++j)
                    acc[i][j] = fmaf(av_[i], bv_[j], acc[i][j]);
        }
        __syncthreads();
    }

    if (mode == 1) {
        #pragma unroll
        for (int i = 0; i < 4; ++i) {
            int m = m0 + ty * 4 + i;
            float4 v;
            v.x = __builtin_amdgcn_exp2f((acc[i][0] + bias[n0 + tx * 4 + 0]) * PS);
            v.y = __builtin_amdgcn_exp2f((acc[i][1] + bias[n0 + tx * 4 + 1]) * PS);
            v.z = __builtin_amdgcn_exp2f((acc[i][2] + bias[n0 + tx * 4 + 2]) * PS);
            v.w = __builtin_amdgcn_exp2f((acc[i][3] + bias[n0 + tx * 4 + 3]) * PS);
            *reinterpret_cast<float4*>(&Es[(size_t)m * AA + n0 + tx * 4]) = v;
        }
    } else if (mode == 0) {
        #pragma unroll
        for (int i = 0; i < 4; ++i)
            #pragma unroll
            for (int j = 0; j < 4; ++j)
                Cs[tx * 4 + j][ty * 4 + i] =
                    __builtin_amdgcn_exp2f((acc[i][j] + bias[n0 + tx * 4 + j]) * PS);
        __syncthreads();
        int row = tid >> 2, part = tid & 3;
        int bb = m0 >> 8;
        int tstart = (m0 & 255) + part * 16;
        float* dst = &EhT[bb * (AA * TT) + (n0 + row) * TT + tstart];
        #pragma unroll
        for (int q = 0; q < 4; ++q) {
            float4 v = *reinterpret_cast<const float4*>(&Cs[row][part * 16 + q * 4]);
            *reinterpret_cast<float4*>(&dst[q * 4]) = v;
        }
    } else {
        int bb = m0 >> 8;
        #pragma unroll
        for (int i = 0; i < 4; ++i) {
            float p = 0.f;
            #pragma unroll
            for (int j = 0; j < 4; ++j) {
                int n = n0 + tx * 4 + j;
                float x = acc[i][j] + bias[n] + ii[bb * AA + n];
                p = fmaf(iv[n], fast_tanh(x), p);
            }
            Cs[ty * 4 + i][tx] = p;
        }
        __syncthreads();
        if (tid < 64) {
            float s = 0.f;
            #pragma unroll
            for (int k = 0; k < 16; ++k) s += Cs[tid][k];
            ipart[blockIdx.y * 2048 + m0 + tid] = s;
        }
    }
}

// ---------------- k3_fused: r12 pairwise-rcp + centering-free softmax --------------------
// weight ∝ exp2(-PS*y); |PS*y| <= PS*Σ|v| < ~75 so exp2 stays in f32 range and the
// largest term of the denominator is >= 2^-75 >> FLT_MIN (no zero-sum).
__global__ __launch_bounds__(512) void k3_fused(const float* __restrict__ SO,
                                                const float* __restrict__ EhT,
                                                const float* __restrict__ Es,
                                                const float* __restrict__ sv_g,
                                                const float* __restrict__ ipart,
                                                float* __restrict__ out_cslot,
                                                float* __restrict__ out_cint,
                                                int npart) {
    const int bid = blockIdx.x;
    const int tid = threadIdx.x;

    __shared__ __align__(16) float est[512][4];   // [a][q]
    __shared__ __align__(16) float sv[512];
    __shared__ __align__(8)  float yp[4][4][256]; // [ah][q][s]
    __shared__ __align__(16) float wlt[256][4];
    __shared__ float reds[4][2];
    __shared__ float redI[256];
    __shared__ float wlI[256];

    const int b = bid & 7;          // XCD-affine
    const int t0 = (bid >> 3) * 4;
    const int sp = tid & 127;       // s-pair index: s = 2*sp, 2*sp+1
    const int ah = tid >> 7;        // 0..3, a-quarter
    const int abase = ah * 128;

    // stage est (transposed gather) + sv
    {
        const float* esrc = &Es[(size_t)(b * 256 + t0) * 512];
        #pragma unroll
        for (int i = tid; i < 2048; i += 512) est[i & 511][i >> 9] = esrc[i];
        sv[tid] = sv_g[tid];
    }
    __syncthreads();

    // ---- score: 128 a x 4 t x 2 s per thread; a-pairs share one rcp ----
    const float* hp = &EhT[((size_t)b * 512 + abase) * 256 + 2 * sp];
    float a00=0.f,a01=0.f,a10=0.f,a11=0.f,a20=0.f,a21=0.f,a30=0.f,a31=0.f;
    float2 h0[4], h1[4];
    #pragma unroll
    for (int u = 0; u < 4; ++u)
        h0[u] = *reinterpret_cast<const float2*>(&hp[u * 256]);

    // one (t) slice of a pair: two s-values, shared va/vb
    #define PAIRT(HA, HB, E1, E2, VA, VB, ACC0, ACC1) do {                         \
        float d1x = fmaf((HA).x, (E1), 1.f);                                       \
        float d2x = fmaf((HB).x, (E2), 1.f);                                       \
        ACC0 = fmaf(fmaf((VA), d2x, (VB) * d1x),                                   \
                    __builtin_amdgcn_rcpf(d1x * d2x), ACC0);                       \
        float d1y = fmaf((HA).y, (E1), 1.f);                                       \
        float d2y = fmaf((HB).y, (E2), 1.f);                                       \
        ACC1 = fmaf(fmaf((VA), d2y, (VB) * d1y),                                   \
                    __builtin_amdgcn_rcpf(d1y * d2y), ACC1);                       \
    } while (0)

    #define SCOREP(A0, H) do {                                                     \
        float4 v4 = *reinterpret_cast<const float4*>(&sv[abase + (A0)]);           \
        float4 e0 = *reinterpret_cast<const float4*>(&est[abase + (A0) + 0][0]);   \
        float4 e1 = *reinterpret_cast<const float4*>(&est[abase + (A0) + 1][0]);   \
        float4 e2 = *reinterpret_cast<const float4*>(&est[abase + (A0) + 2][0]);   \
        float4 e3 = *reinterpret_cast<const float4*>(&est[abase + (A0) + 3][0]);   \
        PAIRT(H[0], H[1], e0.x, e1.x, v4.x, v4.y, a00, a01);                       \
        PAIRT(H[0], H[1], e0.y, e1.y, v4.x, v4.y, a10, a11);                       \
        PAIRT(H[0], H[1], e0.z, e1.z, v4.x, v4.y, a20, a21);                       \
        PAIRT(H[0], H[1], e0.w, e1.w, v4.x, v4.y, a30, a31);                       \
        PAIRT(H[2], H[3], e2.x, e3.x, v4.z, v4.w, a00, a01);                       \
        PAIRT(H[2], H[3], e2.y, e3.y, v4.z, v4.w, a10, a11);                       \
        PAIRT(H[2], H[3], e2.z, e3.z, v4.z, v4.w, a20, a21);                       \
        PAIRT(H[2], H[3], e2.w, e3.w, v4.z, v4.w, a30, a31);                       \
    } while (0)

    for (int a0 = 0; a0 < 128; a0 += 8) {
        #pragma unroll
        for (int u = 0; u < 4; ++u)
            h1[u] = *reinterpret_cast<const float2*>(&hp[(a0 + 4 + u) * 256]);
        SCOREP(a0, h0);
        #pragma unroll
        for (int u = 0; u < 4; ++u)   // over-read at a0=120 stays inside ws (Es region)
            h0[u] = *reinterpret_cast<const float2*>(&hp[(a0 + 8 + u) * 256]);
        SCOREP(a0 + 4, h1);
    }

    *reinterpret_cast<float2*>(&yp[ah][0][2 * sp]) = make_float2(a00, a01);
    *reinterpret_cast<float2*>(&yp[ah][1][2 * sp]) = make_float2(a10, a11);
    *reinterpret_cast<float2*>(&yp[ah][2][2 * sp]) = make_float2(a20, a21);
    *reinterpret_cast<float2*>(&yp[ah][3][2 * sp]) = make_float2(a30, a31);
    __syncthreads();

    // ---- softmax (no centering): group g = ah owns t-row g; s=L and s=L+128 ----
    {
        const int g = ah;
        const int L = sp;
        const int w2 = (tid >> 6) & 1;
        float yL = (yp[0][g][L]       + yp[1][g][L])       + (yp[2][g][L]       + yp[3][g][L]);
        float yH = (yp[0][g][L + 128] + yp[1][g][L + 128]) + (yp[2][g][L + 128] + yp[3][g][L + 128]);
        float eL = __builtin_amdgcn_exp2f(-PS * yL);
        float eH = __builtin_amdgcn_exp2f(-PS * yH);
        float sm = eL + eH;
        #pragma unroll
        for (int off = 1; off < 64; off <<= 1)
            sm += __shfl_xor(sm, off);
        if ((tid & 63) == 0) reds[g][w2] = sm;
        __syncthreads();
        sm = reds[g][0] + reds[g][1];
        float rs = __builtin_amdgcn_rcpf(sm);
        wlt[L][g]       = eL * rs;
        wlt[L + 128][g] = eH * rs;
    }
    __syncthreads();

    // ---- PV: thread owns d = tid, 4 t-rows ----
    {
        const int d = tid;
        const float* sop = &SO[(size_t)b * 256 * 512 + d];
        float c0 = 0.f, c1 = 0.f, c2 = 0.f, c3 = 0.f;
        for (int s0 = 0; s0 < 256; s0 += 4) {
            float so[4];
            #pragma unroll
            for (int u = 0; u < 4; ++u) so[u] = sop[(s0 + u) * 512];
            #pragma unroll
            for (int u = 0; u < 4; ++u) {
                float4 w4 = *reinterpret_cast<const float4*>(&wlt[s0 + u][0]);
                c0 = fmaf(w4.x, so[u], c0);
                c1 = fmaf(w4.y, so[u], c1);
                c2 = fmaf(w4.z, so[u], c2);
                c3 = fmaf(w4.w, so[u], c3);
            }
        }
        float* op = &out_cslot[((size_t)(b * 256 + t0)) * 512 + d];
        op[0] = c0; op[512] = c1; op[1024] = c2; op[1536] = c3;
    }

    // ---- intent: folded into blocks 0..7 (b == bid here) ----
    if (bid < 8) {
        __syncthreads();
        float sc = 0.f;
        if (tid < 256) {
            for (int nb = 0; nb < npart; ++nb) sc += ipart[nb * 2048 + b * 256 + tid];
            redI[tid] = sc;
        }
        __syncthreads();
        for (int off = 128; off > 0; off >>= 1) {
            if (tid < off) redI[tid] = fmaxf(redI[tid], redI[tid + off]);
            __syncthreads();
        }
        float mx = redI[0];
        __syncthreads();
        float e = 0.f;
        if (tid < 256) { e = __builtin_amdgcn_exp2f((sc - mx) * LOG2E); redI[tid] = e; }
        __syncthreads();
        for (int off = 128; off > 0; off >>= 1) {
            if (tid < off) redI[tid] += redI[tid + off];
            __syncthreads();
        }
        if (tid < 256) wlI[tid] = e * __builtin_amdgcn_rcpf(redI[0]);
        __syncthreads();
        const int d = tid;
        float c = 0.f;
        const float* sop = &SO[(size_t)b * 256 * 512 + d];
        for (int s0 = 0; s0 < 256; s0 += 4) {
            float so[4];
            #pragma unroll
            for (int u = 0; u < 4; ++u) so[u] = sop[(s0 + u) * 512];
            #pragma unroll
            for (int u = 0; u < 4; ++u) c = fmaf(wlI[s0 + u], so[u], c);
        }
        out_cint[(size_t)b * 512 + d] = c;
    }
}

extern "C" void kernel_launch(void* const* d_in, const int* in_sizes, int n_in,
                              void* d_out, int out_size, void* d_ws, size_t ws_size,
                              hipStream_t stream) {
    const float* SO  = (const float*)d_in[0];
    const float* FS  = (const float*)d_in[1];
    const float* IV  = (const float*)d_in[2];
    const float* Wih = (const float*)d_in[3];
    const float* bih = (const float*)d_in[4];
    const float* Wii = (const float*)d_in[5];
    const float* bii = (const float*)d_in[6];
    const float* SV  = (const float*)d_in[7];
    const float* Wsh = (const float*)d_in[8];
    const float* bsh = (const float*)d_in[9];
    const float* Wsi = (const float*)d_in[10];
    const float* bsi = (const float*)d_in[11];

    float* ws    = (float*)d_ws;
    float* EhT   = ws;                 // [8][512][256]  exp2'd   1,048,576 f
    float* Es    = ws + 1048576;       // [2048][512]    exp2'd   1,048,576 f
    float* ii    = ws + 2097152;       // [8][512]                4,096 f
    float* ipart = ws + 2101248;       // [16][2048]              32,768 f
    ushort* Ast  = (ushort*)(ws + 2134016);  // [2048][1024] bf16
    ushort* Wt   = (ushort*)(ws + 3182592);  // [1536][1024] bf16
    const size_t NEED = (size_t)3969024 * 4;

    float* out_cslot = (float*)d_out;
    float* out_cint  = out_cslot + BB * TT * DD;

    if (ws_size >= NEED) {
        prep<<<1808, 256, 0, stream>>>(SO, Ast, Wsh, Wsi, Wih, Wt, FS, Wii, bii, ii);
        gemm_mfma<<<dim3(32, 24), 256, 0, stream>>>(Ast, Wt, bsh, bsi, bih, ii, IV,
                                                    EhT, Es, ipart);
        k3_fused<<<512, 512, 0, stream>>>(SO, EhT, Es, SV, ipart, out_cslot, out_cint, 16);
    } else {
        k0_ii<<<dim3(BB, 2), 256, 0, stream>>>(FS, Wii, bii, ii);
        k1_gemm_old<<<dim3(32, 8, 3), 256, 0, stream>>>(SO, Wsh, bsh, Wsi, bsi, Wih, bih,
                                                        ii, IV, EhT, Es, ipart);
        k3_fused<<<512, 512, 0, stream>>>(SO, EhT, Es, SV, ipart, out_cslot, out_cint, 8);
    }
}